// Round 4
// baseline (372.726 us; speedup 1.0000x reference)
//
#include <hip/hip_runtime.h>
#include <math.h>

#define BB 4
#define LL 4096
#define DD 256
#define NROWS (BB*LL)      // 16384
#define CHUNK 32
#define NC (LL/CHUNK)      // 128
#define NB 8192            // counting-sort bins

// ---------------- K1: u_q = Wq^T w, u_k = Wk^T w ----------------
__global__ void k_uvec(const float* __restrict__ Wq, const float* __restrict__ Wk,
                       const float* __restrict__ w, float* __restrict__ u) {
    __shared__ float wl[DD];
    int d = threadIdx.x;
    wl[d] = w[d];
    __syncthreads();
    float aq = 0.f, ak = 0.f;
    #pragma unroll 8
    for (int e = 0; e < DD; ++e) {
        float we = wl[e];
        aq = fmaf(Wq[e*DD + d], we, aq);
        ak = fmaf(Wk[e*DD + d], we, ak);
    }
    u[d] = aq;
    u[DD + d] = ak;
}

// ---------------- K2: a_i = x_i . u_q + b ; c_i = x_i . u_k ----------------
__global__ void k_proj(const float* __restrict__ x, const float* __restrict__ u,
                       const float* __restrict__ bmlp,
                       float* __restrict__ a, float* __restrict__ c) {
    int row = blockIdx.x * 4 + (threadIdx.x >> 6);
    int lane = threadIdx.x & 63;
    float4 xv = ((const float4*)(x + (size_t)row * DD))[lane];
    float4 uq = ((const float4*)u)[lane];
    float4 uk = ((const float4*)(u + DD))[lane];
    float sq = xv.x*uq.x + xv.y*uq.y + xv.z*uq.z + xv.w*uq.w;
    float sk = xv.x*uk.x + xv.y*uk.y + xv.z*uk.z + xv.w*uk.w;
    #pragma unroll
    for (int off = 32; off > 0; off >>= 1) {
        sq += __shfl_down(sq, off);
        sk += __shfl_down(sk, off);
    }
    if (lane == 0) {
        a[row] = sq + bmlp[0];
        c[row] = sk;
    }
}

// ---------------- K3: counting sort by value-bin + SE prefix ----------------
__global__ void __launch_bounds__(1024) k_sortish(const float* __restrict__ c,
        int* __restrict__ binstart_g,       // [BB][NB+2]
        int* __restrict__ perm,             // [BB][LL]
        float* __restrict__ c_sorted, float* __restrict__ e_sorted,
        float* __restrict__ SE,             // [BB][LL+1]
        float* __restrict__ hdr) {          // [BB][2] = {cmin, scale}
    __shared__ float cl[LL];       // 16 KB
    __shared__ int   hist[NB];     // 32 KB
    __shared__ float esl[LL];      // 16 KB
    __shared__ float scrf[64];
    int b = blockIdx.x, tid = threadIdx.x;
    int wave = tid >> 6, lane = tid & 63;
    int* scri = (int*)scrf;

    // 1. load c, find min/max
    float4 cv = ((const float4*)(c + (size_t)b*LL))[tid];
    ((float4*)cl)[tid] = cv;
    float cw[4] = {cv.x, cv.y, cv.z, cv.w};
    float mn = fminf(fminf(cw[0],cw[1]), fminf(cw[2],cw[3]));
    float mx = fmaxf(fmaxf(cw[0],cw[1]), fmaxf(cw[2],cw[3]));
    #pragma unroll
    for (int off = 32; off > 0; off >>= 1) {
        mn = fminf(mn, __shfl_down(mn, off));
        mx = fmaxf(mx, __shfl_down(mx, off));
    }
    if (lane == 0) { scrf[wave] = mn; scrf[32 + wave] = mx; }
    __syncthreads();
    if (wave == 0) {
        float m = (lane < 16) ? scrf[lane]      :  3.4e38f;
        float M = (lane < 16) ? scrf[32 + lane] : -3.4e38f;
        #pragma unroll
        for (int off = 32; off > 0; off >>= 1) {
            m = fminf(m, __shfl_down(m, off));
            M = fmaxf(M, __shfl_down(M, off));
        }
        if (lane == 0) { scrf[0] = m; scrf[1] = M; }
    }
    __syncthreads();
    float cmin = scrf[0], cmax = scrf[1];
    float scale = (float)NB / fmaxf(cmax - cmin, 1e-20f);
    __syncthreads();

    // 2. zero histogram (int4)
    ((int4*)hist)[tid] = make_int4(0,0,0,0);
    ((int4*)hist)[tid + 1024] = make_int4(0,0,0,0);
    __syncthreads();

    // 3. histogram
    int bins[4];
    #pragma unroll
    for (int u = 0; u < 4; ++u) {
        int bi = (int)((cw[u] - cmin) * scale);
        bi = bi < 0 ? 0 : (bi > NB-1 ? NB-1 : bi);
        bins[u] = bi;
        atomicAdd(&hist[bi], 1);
    }
    __syncthreads();

    // 4. exclusive scan of hist (8 bins/thread, then 1024-thread scan)
    int loc[8]; int base = 0;
    #pragma unroll
    for (int j = 0; j < 8; ++j) { loc[j] = base; base += hist[tid*8 + j]; }
    int incl = base;
    #pragma unroll
    for (int off = 1; off < 64; off <<= 1) {
        int t = __shfl_up(incl, off);
        if (lane >= off) incl += t;
    }
    if (lane == 63) scri[wave] = incl;
    __syncthreads();
    if (wave == 0) {
        int v = (lane < 16) ? scri[lane] : 0;
        int s = v;
        #pragma unroll
        for (int off = 1; off < 16; off <<= 1) {
            int t = __shfl_up(s, off);
            if (lane >= off) s += t;
        }
        if (lane < 16) scri[lane] = s - v;   // exclusive wave offsets
    }
    __syncthreads();
    int thread_excl = (incl - base) + scri[wave];
    __syncthreads();                          // all reads of scri/hist done
    #pragma unroll
    for (int j = 0; j < 8; ++j) {
        int bs = thread_excl + loc[j];
        binstart_g[(size_t)b*(NB+2) + tid*8 + j] = bs;
        hist[tid*8 + j] = bs;                // LDS copy for scatter
    }
    if (tid == 0) {
        binstart_g[(size_t)b*(NB+2) + NB]     = LL;
        binstart_g[(size_t)b*(NB+2) + NB + 1] = LL;
        hdr[b*2 + 0] = cmin;
        hdr[b*2 + 1] = scale;
    }
    __syncthreads();

    // 5. scatter (atomic rank within bin; order-independent at boundaries)
    #pragma unroll
    for (int u = 0; u < 4; ++u) {
        int i = tid*4 + u;
        int r = atomicAdd(&hist[bins[u]], 1);
        float e = expf(cmin - cw[u]);         // <= 1 (cw >= cmin)
        perm[(size_t)b*LL + r] = i;
        c_sorted[(size_t)b*LL + r] = cw[u];
        e_sorted[(size_t)b*LL + r] = e;
        esl[r] = e;
    }
    __syncthreads();

    // 6. exclusive prefix SE over esl
    float le[4]; float s0 = 0.f;
    #pragma unroll
    for (int u = 0; u < 4; ++u) { le[u] = s0; s0 += esl[tid*4 + u]; }
    float fincl = s0;
    #pragma unroll
    for (int off = 1; off < 64; off <<= 1) {
        float t = __shfl_up(fincl, off);
        if (lane >= off) fincl += t;
    }
    if (lane == 63) scrf[wave] = fincl;
    __syncthreads();
    if (wave == 0) {
        float v = (lane < 16) ? scrf[lane] : 0.f;
        float s = v;
        #pragma unroll
        for (int off = 1; off < 16; off <<= 1) {
            float t = __shfl_up(s, off);
            if (lane >= off) s += t;
        }
        if (lane < 16) scrf[lane] = s - v;
    }
    __syncthreads();
    float texcl = (fincl - s0) + scrf[wave];
    #pragma unroll
    for (int u = 0; u < 4; ++u)
        SE[(size_t)b*(LL+1) + tid*4 + u] = texcl + le[u];
    if (tid == 1023) SE[(size_t)b*(LL+1) + LL] = texcl + s0;
}

// ---------------- K4: V = x @ Wv^T ----------------
// 64 rows x 256 cols (full N) per block, 512 threads, grid = 256 = 1 block/CU
// (8 waves/CU = 2/SIMD). Micro: 4 rows (stride 16) x 8 cols (stride 32).
// LDS: A[m][kc] float4 (writes span 8 bank groups; reads are 2-addr broadcast
// = free). B[kc][n ^ kc] XOR-swizzle: staging writes (n fixed, kc 0..7) span
// all 8 groups; fragment reads (kc fixed, n = tc+32s) = 4 addr/group = minimum
// phases. Register-prefetch double buffer, one barrier per K-step.
__global__ void __launch_bounds__(512, 2) k_gemm_v(const float* __restrict__ x,
        const float* __restrict__ Wv, float* __restrict__ V) {
    __shared__ float4 As[2][64*8];     // 8 KB per buf
    __shared__ float4 Bs[2][8*256];    // 32 KB per buf
    const int tid = threadIdx.x;
    const int rowBase = blockIdx.x * 64;
    const int tr = tid >> 5;           // [0,16): rows tr + 16r
    const int tc = tid & 31;           // [0,32): cols tc + 32s
    const int mA = tid >> 3, kA = tid & 7;   // A staging: 1 float4/thread

    float4 pa;
    float4 pb[4];
    // prologue: tile 0
    pa = *(const float4*)(x + (size_t)(rowBase + mA) * DD + 4*kA);
    #pragma unroll
    for (int rep = 0; rep < 4; ++rep) {
        int idx = tid + 512*rep;
        int nB = idx >> 3, kB = idx & 7;
        pb[rep] = *(const float4*)(Wv + (size_t)nB * DD + 4*kB);
    }
    As[0][mA*8 + kA] = pa;
    #pragma unroll
    for (int rep = 0; rep < 4; ++rep) {
        int idx = tid + 512*rep;
        int nB = idx >> 3, kB = idx & 7;
        Bs[0][kB*256 + (nB ^ kB)] = pb[rep];
    }
    __syncthreads();

    float acc[4][8];
    #pragma unroll
    for (int r = 0; r < 4; ++r)
        #pragma unroll
        for (int s = 0; s < 8; ++s) acc[r][s] = 0.f;

    for (int k0 = 0; k0 < 8; ++k0) {
        const int cur = k0 & 1;
        if (k0 < 7) {
            const int kb = (k0 + 1) * 32;
            pa = *(const float4*)(x + (size_t)(rowBase + mA) * DD + kb + 4*kA);
            #pragma unroll
            for (int rep = 0; rep < 4; ++rep) {
                int idx = tid + 512*rep;
                int nB = idx >> 3, kB = idx & 7;
                pb[rep] = *(const float4*)(Wv + (size_t)nB * DD + kb + 4*kB);
            }
        }
        #pragma unroll
        for (int kc = 0; kc < 8; ++kc) {
            float4 af[4], bf[8];
            #pragma unroll
            for (int r = 0; r < 4; ++r) af[r] = As[cur][(tr + 16*r)*8 + kc];
            #pragma unroll
            for (int s = 0; s < 8; ++s) bf[s] = Bs[cur][kc*256 + ((tc + 32*s) ^ kc)];
            #pragma unroll
            for (int r = 0; r < 4; ++r)
                #pragma unroll
                for (int s = 0; s < 8; ++s) {
                    acc[r][s] = fmaf(af[r].x, bf[s].x, acc[r][s]);
                    acc[r][s] = fmaf(af[r].y, bf[s].y, acc[r][s]);
                    acc[r][s] = fmaf(af[r].z, bf[s].z, acc[r][s]);
                    acc[r][s] = fmaf(af[r].w, bf[s].w, acc[r][s]);
                }
        }
        if (k0 < 7) {
            As[cur^1][mA*8 + kA] = pa;
            #pragma unroll
            for (int rep = 0; rep < 4; ++rep) {
                int idx = tid + 512*rep;
                int nB = idx >> 3, kB = idx & 7;
                Bs[cur^1][kB*256 + (nB ^ kB)] = pb[rep];
            }
            __syncthreads();
        }
    }
    #pragma unroll
    for (int r = 0; r < 4; ++r) {
        size_t rowo = (size_t)(rowBase + tr + 16*r) * DD;
        #pragma unroll
        for (int s = 0; s < 8; ++s)
            V[rowo + tc + 32*s] = acc[r][s];
    }
}

// ---------------- K5: chunked exclusive prefix over V in rank order ----------------
__global__ void k_scan(const float* __restrict__ V, const int* __restrict__ perm,
        const float* __restrict__ e_sorted,
        float* __restrict__ Pl, float* __restrict__ Pel,
        float* __restrict__ Tp, float* __restrict__ Te) {
    int b = blockIdx.y, q = blockIdx.x;
    int d = threadIdx.x;
    __shared__ int pj[CHUNK];
    __shared__ float pe[CHUNK];
    if (d < CHUNK) {
        pj[d] = perm[(size_t)b*LL + q*CHUNK + d];
        pe[d] = e_sorted[(size_t)b*LL + q*CHUNK + d];
    }
    __syncthreads();
    float vr[CHUNK];
    #pragma unroll
    for (int r = 0; r < CHUNK; ++r)
        vr[r] = V[((size_t)b*LL + pj[r]) * DD + d];
    float acc = 0.f, acce = 0.f;
    size_t kb = (size_t)b*LL + (size_t)q*CHUNK;
    #pragma unroll
    for (int r = 0; r < CHUNK; ++r) {
        size_t o = (kb + r) * DD + d;
        Pl[o]  = acc;
        Pel[o] = acce;
        acc += vr[r];
        acce = fmaf(pe[r], vr[r], acce);
    }
    size_t to = ((size_t)b*NC + q) * DD + d;
    Tp[to] = acc;
    Te[to] = acce;
}

// ---------------- K6: scan chunk totals -> chunk bases (+ grand total) ----------------
__global__ void k_base(const float* __restrict__ Tp, const float* __restrict__ Te,
        float* __restrict__ baseP, float* __restrict__ basePe) {
    int b = blockIdx.x, d = threadIdx.x;
    float acc = 0.f, acce = 0.f;
    #pragma unroll 16
    for (int q = 0; q < NC; ++q) {
        size_t o = ((size_t)b*(NC+1) + q) * DD + d;
        baseP[o] = acc; basePe[o] = acce;
        size_t ti = ((size_t)b*NC + q) * DD + d;
        acc += Tp[ti]; acce += Te[ti];
    }
    size_t o = ((size_t)b*(NC+1) + NC) * DD + d;
    baseP[o] = acc; basePe[o] = acce;
}

// ---------------- K7: per-row output, O(1) bin lookup + exact boundary fix ----------------
__global__ void k_out(const float* __restrict__ a, const float* __restrict__ hdr,
                      const int* __restrict__ binstart,
                      const float* __restrict__ c_sorted, const float* __restrict__ e_sorted,
                      const int* __restrict__ perm, const float* __restrict__ V,
                      const float* __restrict__ SE,
                      const float* __restrict__ Pl, const float* __restrict__ Pel,
                      const float* __restrict__ baseP, const float* __restrict__ basePe,
                      float* __restrict__ out) {
    int row = blockIdx.x * 4 + (threadIdx.x >> 6);
    int lane = threadIdx.x & 63;
    int b = row >> 12;
    float ai = a[row];
    float cmin = hdr[b*2 + 0], scale = hdr[b*2 + 1];
    float t = (ai - cmin) * scale;
    int ib = t < 0.f ? 0 : (t >= (float)NB ? NB : (int)t);
    int k    = binstart[(size_t)b*(NB+2) + ib];
    int kend = binstart[(size_t)b*(NB+2) + ib + 1];
    float alpha = expf(cmin - ai);
    float Z = fmaf(alpha, (float)(LL - k), SE[(size_t)b*(LL+1) + k]);
    size_t db = (size_t)lane * 4;
    size_t totoff = ((size_t)b * (NC+1) + NC) * DD + db;
    float4 ptot  = *(const float4*)(baseP  + totoff);
    float4 pk, pek;
    if (k < LL) {
        int q = k >> 5;
        size_t po = ((size_t)b * LL + k) * DD + db;
        size_t bo = ((size_t)b * (NC+1) + q) * DD + db;
        float4 pl = *(const float4*)(Pl    + po);
        float4 bp = *(const float4*)(baseP + bo);
        float4 pe = *(const float4*)(Pel    + po);
        float4 be = *(const float4*)(basePe + bo);
        pk.x = pl.x + bp.x; pk.y = pl.y + bp.y; pk.z = pl.z + bp.z; pk.w = pl.w + bp.w;
        pek.x = pe.x + be.x; pek.y = pe.y + be.y; pek.z = pe.z + be.z; pek.w = pe.w + be.w;
    } else {
        pk = ptot;
        float4 pt = *(const float4*)(basePe + totoff);
        pek = pt;
    }
    float4 num;
    num.x = fmaf(alpha, ptot.x - pk.x, pek.x);
    num.y = fmaf(alpha, ptot.y - pk.y, pek.y);
    num.z = fmaf(alpha, ptot.z - pk.z, pek.z);
    num.w = fmaf(alpha, ptot.w - pk.w, pek.w);
    // exact correction for keys sharing a_i's bin (expected ~1-3 elements)
    for (int r = k; r < kend; ++r) {
        float cr = c_sorted[(size_t)b*LL + r];
        if (cr < ai) {
            float w = e_sorted[(size_t)b*LL + r] - alpha;
            int j = perm[(size_t)b*LL + r];
            float4 v = *(const float4*)(V + ((size_t)b*LL + j) * DD + db);
            num.x = fmaf(w, v.x, num.x);
            num.y = fmaf(w, v.y, num.y);
            num.z = fmaf(w, v.z, num.z);
            num.w = fmaf(w, v.w, num.w);
            Z += w;
        }
    }
    float invZ = 1.f / Z;
    float4 o;
    o.x = num.x * invZ; o.y = num.y * invZ; o.z = num.z * invZ; o.w = num.w * invZ;
    *(float4*)(out + (size_t)row * DD + db) = o;
}

extern "C" void kernel_launch(void* const* d_in, const int* in_sizes, int n_in,
                              void* d_out, int out_size, void* d_ws, size_t ws_size,
                              hipStream_t stream) {
    const float* x  = (const float*)d_in[0];
    const float* Wq = (const float*)d_in[1];
    const float* Wk = (const float*)d_in[2];
    const float* Wv = (const float*)d_in[3];
    const float* wm = (const float*)d_in[4];
    const float* bm = (const float*)d_in[5];
    float* out = (float*)d_out;
    float* ws = (float*)d_ws;

    size_t off = 0;
    auto alloc = [&](size_t n) {
        float* p = ws + off;
        off += (n + 255) & ~(size_t)255;
        return p;
    };
    float* u        = alloc(2*DD);
    float* a        = alloc(NROWS);
    float* c        = alloc(NROWS);
    float* c_sorted = alloc(NROWS);
    float* e_sorted = alloc(NROWS);
    float* SE       = alloc((size_t)BB*(LL+1));
    int*   perm     = (int*)alloc(NROWS);
    int*   binstart = (int*)alloc((size_t)BB*(NB+2));
    float* hdr      = alloc(2*BB);
    float* V        = alloc((size_t)NROWS*DD);
    float* Pl       = alloc((size_t)NROWS*DD);
    float* Pel      = alloc((size_t)NROWS*DD);
    float* Tp       = alloc((size_t)BB*NC*DD);
    float* Te       = alloc((size_t)BB*NC*DD);
    float* baseP    = alloc((size_t)BB*(NC+1)*DD);
    float* basePe   = alloc((size_t)BB*(NC+1)*DD);

    hipLaunchKernelGGL(k_uvec, dim3(1), dim3(DD), 0, stream, Wq, Wk, wm, u);
    hipLaunchKernelGGL(k_proj, dim3(NROWS/4), dim3(256), 0, stream, x, u, bm, a, c);
    hipLaunchKernelGGL(k_sortish, dim3(BB), dim3(1024), 0, stream,
                       c, binstart, perm, c_sorted, e_sorted, SE, hdr);
    hipLaunchKernelGGL(k_gemm_v, dim3(NROWS/64), dim3(512), 0, stream, x, Wv, V);
    hipLaunchKernelGGL(k_scan, dim3(NC, BB), dim3(DD), 0, stream, V, perm, e_sorted, Pl, Pel, Tp, Te);
    hipLaunchKernelGGL(k_base, dim3(BB), dim3(DD), 0, stream, Tp, Te, baseP, basePe);
    hipLaunchKernelGGL(k_out, dim3(NROWS/4), dim3(256), 0, stream,
                       a, hdr, binstart, c_sorted, e_sorted, perm, V,
                       SE, Pl, Pel, baseP, basePe, out);
}

// Round 5
// 165.624 us; speedup vs baseline: 2.2504x; 2.2504x over previous
//
#include <hip/hip_runtime.h>
#include <math.h>

#define BB 4
#define LL 4096
#define DD 256
#define NROWS (BB*LL)      // 16384
#define CHUNK 32
#define NC (LL/CHUNK)      // 128
#define NB 8192            // counting-sort bins

// ---------------- K1: u_q = Wq^T w, u_k = Wk^T w ----------------
__global__ void k_uvec(const float* __restrict__ Wq, const float* __restrict__ Wk,
                       const float* __restrict__ w, float* __restrict__ u) {
    __shared__ float wl[DD];
    int d = threadIdx.x;
    wl[d] = w[d];
    __syncthreads();
    float aq = 0.f, ak = 0.f;
    #pragma unroll 8
    for (int e = 0; e < DD; ++e) {
        float we = wl[e];
        aq = fmaf(Wq[e*DD + d], we, aq);
        ak = fmaf(Wk[e*DD + d], we, ak);
    }
    u[d] = aq;
    u[DD + d] = ak;
}

// ---------------- K2: a_i = x_i . u_q + b ; c_i = x_i . u_k ----------------
__global__ void k_proj(const float* __restrict__ x, const float* __restrict__ u,
                       const float* __restrict__ bmlp,
                       float* __restrict__ a, float* __restrict__ c) {
    int row = blockIdx.x * 4 + (threadIdx.x >> 6);
    int lane = threadIdx.x & 63;
    float4 xv = ((const float4*)(x + (size_t)row * DD))[lane];
    float4 uq = ((const float4*)u)[lane];
    float4 uk = ((const float4*)(u + DD))[lane];
    float sq = xv.x*uq.x + xv.y*uq.y + xv.z*uq.z + xv.w*uq.w;
    float sk = xv.x*uk.x + xv.y*uk.y + xv.z*uk.z + xv.w*uk.w;
    #pragma unroll
    for (int off = 32; off > 0; off >>= 1) {
        sq += __shfl_down(sq, off);
        sk += __shfl_down(sk, off);
    }
    if (lane == 0) {
        a[row] = sq + bmlp[0];
        c[row] = sk;
    }
}

// ---------------- K3: counting sort by value-bin + SE prefix ----------------
__global__ void __launch_bounds__(1024) k_sortish(const float* __restrict__ c,
        int* __restrict__ binstart_g,       // [BB][NB+2]
        int* __restrict__ perm,             // [BB][LL]
        float* __restrict__ c_sorted, float* __restrict__ e_sorted,
        float* __restrict__ SE,             // [BB][LL+1]
        float* __restrict__ hdr) {          // [BB][2] = {cmin, scale}
    __shared__ float cl[LL];       // 16 KB
    __shared__ int   hist[NB];     // 32 KB
    __shared__ float esl[LL];      // 16 KB
    __shared__ float scrf[64];
    int b = blockIdx.x, tid = threadIdx.x;
    int wave = tid >> 6, lane = tid & 63;
    int* scri = (int*)scrf;

    // 1. load c, find min/max
    float4 cv = ((const float4*)(c + (size_t)b*LL))[tid];
    ((float4*)cl)[tid] = cv;
    float cw[4] = {cv.x, cv.y, cv.z, cv.w};
    float mn = fminf(fminf(cw[0],cw[1]), fminf(cw[2],cw[3]));
    float mx = fmaxf(fmaxf(cw[0],cw[1]), fmaxf(cw[2],cw[3]));
    #pragma unroll
    for (int off = 32; off > 0; off >>= 1) {
        mn = fminf(mn, __shfl_down(mn, off));
        mx = fmaxf(mx, __shfl_down(mx, off));
    }
    if (lane == 0) { scrf[wave] = mn; scrf[32 + wave] = mx; }
    __syncthreads();
    if (wave == 0) {
        float m = (lane < 16) ? scrf[lane]      :  3.4e38f;
        float M = (lane < 16) ? scrf[32 + lane] : -3.4e38f;
        #pragma unroll
        for (int off = 32; off > 0; off >>= 1) {
            m = fminf(m, __shfl_down(m, off));
            M = fmaxf(M, __shfl_down(M, off));
        }
        if (lane == 0) { scrf[0] = m; scrf[1] = M; }
    }
    __syncthreads();
    float cmin = scrf[0], cmax = scrf[1];
    float scale = (float)NB / fmaxf(cmax - cmin, 1e-20f);
    __syncthreads();

    // 2. zero histogram (int4)
    ((int4*)hist)[tid] = make_int4(0,0,0,0);
    ((int4*)hist)[tid + 1024] = make_int4(0,0,0,0);
    __syncthreads();

    // 3. histogram
    int bins[4];
    #pragma unroll
    for (int u = 0; u < 4; ++u) {
        int bi = (int)((cw[u] - cmin) * scale);
        bi = bi < 0 ? 0 : (bi > NB-1 ? NB-1 : bi);
        bins[u] = bi;
        atomicAdd(&hist[bi], 1);
    }
    __syncthreads();

    // 4. exclusive scan of hist (8 bins/thread, then 1024-thread scan)
    int loc[8]; int base = 0;
    #pragma unroll
    for (int j = 0; j < 8; ++j) { loc[j] = base; base += hist[tid*8 + j]; }
    int incl = base;
    #pragma unroll
    for (int off = 1; off < 64; off <<= 1) {
        int t = __shfl_up(incl, off);
        if (lane >= off) incl += t;
    }
    if (lane == 63) scri[wave] = incl;
    __syncthreads();
    if (wave == 0) {
        int v = (lane < 16) ? scri[lane] : 0;
        int s = v;
        #pragma unroll
        for (int off = 1; off < 16; off <<= 1) {
            int t = __shfl_up(s, off);
            if (lane >= off) s += t;
        }
        if (lane < 16) scri[lane] = s - v;   // exclusive wave offsets
    }
    __syncthreads();
    int thread_excl = (incl - base) + scri[wave];
    __syncthreads();                          // all reads of scri/hist done
    #pragma unroll
    for (int j = 0; j < 8; ++j) {
        int bs = thread_excl + loc[j];
        binstart_g[(size_t)b*(NB+2) + tid*8 + j] = bs;
        hist[tid*8 + j] = bs;                // LDS copy for scatter
    }
    if (tid == 0) {
        binstart_g[(size_t)b*(NB+2) + NB]     = LL;
        binstart_g[(size_t)b*(NB+2) + NB + 1] = LL;
        hdr[b*2 + 0] = cmin;
        hdr[b*2 + 1] = scale;
    }
    __syncthreads();

    // 5. scatter (atomic rank within bin; order-independent at boundaries)
    #pragma unroll
    for (int u = 0; u < 4; ++u) {
        int i = tid*4 + u;
        int r = atomicAdd(&hist[bins[u]], 1);
        float e = expf(cmin - cw[u]);         // <= 1 (cw >= cmin)
        perm[(size_t)b*LL + r] = i;
        c_sorted[(size_t)b*LL + r] = cw[u];
        e_sorted[(size_t)b*LL + r] = e;
        esl[r] = e;
    }
    __syncthreads();

    // 6. exclusive prefix SE over esl
    float le[4]; float s0 = 0.f;
    #pragma unroll
    for (int u = 0; u < 4; ++u) { le[u] = s0; s0 += esl[tid*4 + u]; }
    float fincl = s0;
    #pragma unroll
    for (int off = 1; off < 64; off <<= 1) {
        float t = __shfl_up(fincl, off);
        if (lane >= off) fincl += t;
    }
    if (lane == 63) scrf[wave] = fincl;
    __syncthreads();
    if (wave == 0) {
        float v = (lane < 16) ? scrf[lane] : 0.f;
        float s = v;
        #pragma unroll
        for (int off = 1; off < 16; off <<= 1) {
            float t = __shfl_up(s, off);
            if (lane >= off) s += t;
        }
        if (lane < 16) scrf[lane] = s - v;
    }
    __syncthreads();
    float texcl = (fincl - s0) + scrf[wave];
    #pragma unroll
    for (int u = 0; u < 4; ++u)
        SE[(size_t)b*(LL+1) + tid*4 + u] = texcl + le[u];
    if (tid == 1023) SE[(size_t)b*(LL+1) + LL] = texcl + s0;
}

// ---------------- K4: V = x @ Wv^T ----------------
// 64x128 tile, 256 threads (16x16), micro 4 rows (ty+16r) x 8 cols (tx+16s).
// LDS: padded stride-9 [m][kc] float4 layout. Bank math:
//   slot 9m+kc -> bank group 4(m+kc) mod 32.
//   Staging writes (idx=tid: m=idx>>3, kc=idx&7): each 8-lane quantum covers
//   all 8 bank groups -> conflict-free b128 writes.
//   A reads (m=ty+16r, kc fixed): 4 distinct addrs, 4 distinct groups, 16-way
//   broadcast -> free. B reads (n=tx+16s): 16 addrs, 2 per group -> free (m136).
// Single-buffered (round-3 structure: no held prefetch regs -> no spill).
__global__ void __launch_bounds__(256) k_gemm_v(const float* __restrict__ x,
        const float* __restrict__ Wv, float* __restrict__ V) {
    __shared__ float4 As[64*9];      // 9 KB
    __shared__ float4 Bs[128*9];     // 18 KB
    const int tid = threadIdx.x;
    const int rowBase = blockIdx.x * 64;
    const int colBase = blockIdx.y * 128;
    const int ty = tid >> 4;         // [0,16): rows ty+16r? no: rows ty + 16r, r<4 -> 64
    const int tx = tid & 15;         // [0,16): cols tx + 16s, s<8 -> 128

    float acc[4][8];
    #pragma unroll
    for (int r = 0; r < 4; ++r)
        #pragma unroll
        for (int s = 0; s < 8; ++s) acc[r][s] = 0.f;

    for (int k0 = 0; k0 < DD; k0 += 32) {
        __syncthreads();
        // stage A: 64 rows x 8 float4 = 512 -> 2 per thread
        #pragma unroll
        for (int rep = 0; rep < 2; ++rep) {
            int idx = tid + 256*rep;
            int m = idx >> 3, kc = idx & 7;
            As[m*9 + kc] = *(const float4*)(x + (size_t)(rowBase + m) * DD + k0 + 4*kc);
        }
        // stage B: 128 rows x 8 float4 = 1024 -> 4 per thread
        #pragma unroll
        for (int rep = 0; rep < 4; ++rep) {
            int idx = tid + 256*rep;
            int n = idx >> 3, kc = idx & 7;
            Bs[n*9 + kc] = *(const float4*)(Wv + (size_t)(colBase + n) * DD + k0 + 4*kc);
        }
        __syncthreads();
        #pragma unroll
        for (int kc = 0; kc < 8; ++kc) {
            float4 af[4], bf[8];
            #pragma unroll
            for (int r = 0; r < 4; ++r) af[r] = As[(ty + 16*r)*9 + kc];
            #pragma unroll
            for (int s = 0; s < 8; ++s) bf[s] = Bs[(tx + 16*s)*9 + kc];
            #pragma unroll
            for (int r = 0; r < 4; ++r)
                #pragma unroll
                for (int s = 0; s < 8; ++s) {
                    acc[r][s] = fmaf(af[r].x, bf[s].x, acc[r][s]);
                    acc[r][s] = fmaf(af[r].y, bf[s].y, acc[r][s]);
                    acc[r][s] = fmaf(af[r].z, bf[s].z, acc[r][s]);
                    acc[r][s] = fmaf(af[r].w, bf[s].w, acc[r][s]);
                }
        }
    }
    #pragma unroll
    for (int r = 0; r < 4; ++r) {
        size_t rowo = (size_t)(rowBase + ty + 16*r) * DD + colBase;
        #pragma unroll
        for (int s = 0; s < 8; ++s)
            V[rowo + tx + 16*s] = acc[r][s];
    }
}

// ---------------- K5: chunked exclusive prefix over V in rank order ----------------
__global__ void k_scan(const float* __restrict__ V, const int* __restrict__ perm,
        const float* __restrict__ e_sorted,
        float* __restrict__ Pl, float* __restrict__ Pel,
        float* __restrict__ Tp, float* __restrict__ Te) {
    int b = blockIdx.y, q = blockIdx.x;
    int d = threadIdx.x;
    __shared__ int pj[CHUNK];
    __shared__ float pe[CHUNK];
    if (d < CHUNK) {
        pj[d] = perm[(size_t)b*LL + q*CHUNK + d];
        pe[d] = e_sorted[(size_t)b*LL + q*CHUNK + d];
    }
    __syncthreads();
    float vr[CHUNK];
    #pragma unroll
    for (int r = 0; r < CHUNK; ++r)
        vr[r] = V[((size_t)b*LL + pj[r]) * DD + d];
    float acc = 0.f, acce = 0.f;
    size_t kb = (size_t)b*LL + (size_t)q*CHUNK;
    #pragma unroll
    for (int r = 0; r < CHUNK; ++r) {
        size_t o = (kb + r) * DD + d;
        Pl[o]  = acc;
        Pel[o] = acce;
        acc += vr[r];
        acce = fmaf(pe[r], vr[r], acce);
    }
    size_t to = ((size_t)b*NC + q) * DD + d;
    Tp[to] = acc;
    Te[to] = acce;
}

// ---------------- K6: scan chunk totals -> chunk bases (+ grand total) ----------------
__global__ void k_base(const float* __restrict__ Tp, const float* __restrict__ Te,
        float* __restrict__ baseP, float* __restrict__ basePe) {
    int b = blockIdx.x, d = threadIdx.x;
    float acc = 0.f, acce = 0.f;
    #pragma unroll 16
    for (int q = 0; q < NC; ++q) {
        size_t o = ((size_t)b*(NC+1) + q) * DD + d;
        baseP[o] = acc; basePe[o] = acce;
        size_t ti = ((size_t)b*NC + q) * DD + d;
        acc += Tp[ti]; acce += Te[ti];
    }
    size_t o = ((size_t)b*(NC+1) + NC) * DD + d;
    baseP[o] = acc; basePe[o] = acce;
}

// ---------------- K7: per-row output, O(1) bin lookup + exact boundary fix ----------------
__global__ void k_out(const float* __restrict__ a, const float* __restrict__ hdr,
                      const int* __restrict__ binstart,
                      const float* __restrict__ c_sorted, const float* __restrict__ e_sorted,
                      const int* __restrict__ perm, const float* __restrict__ V,
                      const float* __restrict__ SE,
                      const float* __restrict__ Pl, const float* __restrict__ Pel,
                      const float* __restrict__ baseP, const float* __restrict__ basePe,
                      float* __restrict__ out) {
    int row = blockIdx.x * 4 + (threadIdx.x >> 6);
    int lane = threadIdx.x & 63;
    int b = row >> 12;
    float ai = a[row];
    float cmin = hdr[b*2 + 0], scale = hdr[b*2 + 1];
    float t = (ai - cmin) * scale;
    int ib = t < 0.f ? 0 : (t >= (float)NB ? NB : (int)t);
    int k    = binstart[(size_t)b*(NB+2) + ib];
    int kend = binstart[(size_t)b*(NB+2) + ib + 1];
    float alpha = expf(cmin - ai);
    float Z = fmaf(alpha, (float)(LL - k), SE[(size_t)b*(LL+1) + k]);
    size_t db = (size_t)lane * 4;
    size_t totoff = ((size_t)b * (NC+1) + NC) * DD + db;
    float4 ptot  = *(const float4*)(baseP  + totoff);
    float4 pk, pek;
    if (k < LL) {
        int q = k >> 5;
        size_t po = ((size_t)b * LL + k) * DD + db;
        size_t bo = ((size_t)b * (NC+1) + q) * DD + db;
        float4 pl = *(const float4*)(Pl    + po);
        float4 bp = *(const float4*)(baseP + bo);
        float4 pe = *(const float4*)(Pel    + po);
        float4 be = *(const float4*)(basePe + bo);
        pk.x = pl.x + bp.x; pk.y = pl.y + bp.y; pk.z = pl.z + bp.z; pk.w = pl.w + bp.w;
        pek.x = pe.x + be.x; pek.y = pe.y + be.y; pek.z = pe.z + be.z; pek.w = pe.w + be.w;
    } else {
        pk = ptot;
        float4 pt = *(const float4*)(basePe + totoff);
        pek = pt;
    }
    float4 num;
    num.x = fmaf(alpha, ptot.x - pk.x, pek.x);
    num.y = fmaf(alpha, ptot.y - pk.y, pek.y);
    num.z = fmaf(alpha, ptot.z - pk.z, pek.z);
    num.w = fmaf(alpha, ptot.w - pk.w, pek.w);
    // exact correction for keys sharing a_i's bin (expected ~1-3 elements)
    for (int r = k; r < kend; ++r) {
        float cr = c_sorted[(size_t)b*LL + r];
        if (cr < ai) {
            float w = e_sorted[(size_t)b*LL + r] - alpha;
            int j = perm[(size_t)b*LL + r];
            float4 v = *(const float4*)(V + ((size_t)b*LL + j) * DD + db);
            num.x = fmaf(w, v.x, num.x);
            num.y = fmaf(w, v.y, num.y);
            num.z = fmaf(w, v.z, num.z);
            num.w = fmaf(w, v.w, num.w);
            Z += w;
        }
    }
    float invZ = 1.f / Z;
    float4 o;
    o.x = num.x * invZ; o.y = num.y * invZ; o.z = num.z * invZ; o.w = num.w * invZ;
    *(float4*)(out + (size_t)row * DD + db) = o;
}

extern "C" void kernel_launch(void* const* d_in, const int* in_sizes, int n_in,
                              void* d_out, int out_size, void* d_ws, size_t ws_size,
                              hipStream_t stream) {
    const float* x  = (const float*)d_in[0];
    const float* Wq = (const float*)d_in[1];
    const float* Wk = (const float*)d_in[2];
    const float* Wv = (const float*)d_in[3];
    const float* wm = (const float*)d_in[4];
    const float* bm = (const float*)d_in[5];
    float* out = (float*)d_out;
    float* ws = (float*)d_ws;

    size_t off = 0;
    auto alloc = [&](size_t n) {
        float* p = ws + off;
        off += (n + 255) & ~(size_t)255;
        return p;
    };
    float* u        = alloc(2*DD);
    float* a        = alloc(NROWS);
    float* c        = alloc(NROWS);
    float* c_sorted = alloc(NROWS);
    float* e_sorted = alloc(NROWS);
    float* SE       = alloc((size_t)BB*(LL+1));
    int*   perm     = (int*)alloc(NROWS);
    int*   binstart = (int*)alloc((size_t)BB*(NB+2));
    float* hdr      = alloc(2*BB);
    float* V        = alloc((size_t)NROWS*DD);
    float* Pl       = alloc((size_t)NROWS*DD);
    float* Pel      = alloc((size_t)NROWS*DD);
    float* Tp       = alloc((size_t)BB*NC*DD);
    float* Te       = alloc((size_t)BB*NC*DD);
    float* baseP    = alloc((size_t)BB*(NC+1)*DD);
    float* basePe   = alloc((size_t)BB*(NC+1)*DD);

    hipLaunchKernelGGL(k_uvec, dim3(1), dim3(DD), 0, stream, Wq, Wk, wm, u);
    hipLaunchKernelGGL(k_proj, dim3(NROWS/4), dim3(256), 0, stream, x, u, bm, a, c);
    hipLaunchKernelGGL(k_sortish, dim3(BB), dim3(1024), 0, stream,
                       c, binstart, perm, c_sorted, e_sorted, SE, hdr);
    hipLaunchKernelGGL(k_gemm_v, dim3(NROWS/64, DD/128), dim3(256), 0, stream, x, Wv, V);
    hipLaunchKernelGGL(k_scan, dim3(NC, BB), dim3(DD), 0, stream, V, perm, e_sorted, Pl, Pel, Tp, Te);
    hipLaunchKernelGGL(k_base, dim3(BB), dim3(DD), 0, stream, Tp, Te, baseP, basePe);
    hipLaunchKernelGGL(k_out, dim3(NROWS/4), dim3(256), 0, stream,
                       a, hdr, binstart, c_sorted, e_sorted, perm, V,
                       SE, Pl, Pel, baseP, basePe, out);
}